// Round 5
// baseline (498.343 us; speedup 1.0000x reference)
//
#include <hip/hip_runtime.h>

// Problem constants
#define NSAMP 262144
#define CCLS 128
#define DDIM 256
#define EPSF 1e-8f

// ws byte offsets (16B-aligned where vector-accessed)
#define OFF_COUNTS   0u          // 128 * u32
#define OFF_G        2048u       // 128x128 f32
#define OFF_W        67584u      // 128x128 f32 (G^-1)
#define OFF_TT       133120u     // 256x128 f32 (T transposed)
#define OFF_MRAW     264192u     // 128x256 f32 (class means, unprojected)
#define OFF_B        395264u     // 128x128 f32 (Mraw @ T^T)
#define OFF_ZT       460800u     // 128x128 f32 (W @ B^T)
#define OFF_M        526336u     // 128x128 f32 (B W B^T)
#define OFF_LAB      1048576u    // 262144 u8 labels (255 = ungated)
#define OFF_BIG      1644288u    // partial slabs, 32768 f32 each
#define SLAB_FLOATS  32768

// ---------------------------------------------------------------------------
// KG: 4 blocks. Block g computes rows [32g,32g+32) of G = T*T^T and writes
//     T^T chunk g.
// ---------------------------------------------------------------------------
extern "C" __global__ __launch_bounds__(1024)
void kg_gram(const float* __restrict__ T, char* __restrict__ ws)
{
    __shared__ float Tl[64][132];
    const int g = blockIdx.x, tid = threadIdx.x;
    float* Tt = (float*)(ws + OFF_TT);
    float* G  = (float*)(ws + OFF_G);
    float a0[8], a1[8];
    #pragma unroll
    for (int j = 0; j < 8; ++j) { a0[j] = 0.f; a1[j] = 0.f; }
    const int Lr = 2 * (tid >> 4);
    const int c0 = 8 * (tid & 15);
    for (int ch = 0; ch < 4; ++ch) {
        for (int i = tid; i < 8192; i += 1024) {
            int cc = i >> 6, dd = i & 63;
            Tl[dd][cc] = T[cc * 256 + ch * 64 + dd];
        }
        __syncthreads();
        if (g == ch) {
            for (int i = tid; i < 8192; i += 1024) {
                int c2 = i & 127, d2 = i >> 7;
                Tt[(ch * 64 + d2) * 128 + c2] = Tl[d2][c2];
            }
        }
        if (tid < 256) {
            for (int dd = 0; dd < 64; ++dd) {
                float r0 = Tl[dd][32 * g + Lr];
                float r1 = Tl[dd][32 * g + Lr + 1];
                float cv[8];
                *(float4*)&cv[0] = *(const float4*)&Tl[dd][c0];
                *(float4*)&cv[4] = *(const float4*)&Tl[dd][c0 + 4];
                #pragma unroll
                for (int j = 0; j < 8; ++j) { a0[j] += r0 * cv[j]; a1[j] += r1 * cv[j]; }
            }
        }
        __syncthreads();
    }
    if (tid < 256) {
        int gr = 32 * g + Lr;
        *(float4*)&G[gr * 128 + c0]           = make_float4(a0[0], a0[1], a0[2], a0[3]);
        *(float4*)&G[gr * 128 + c0 + 4]       = make_float4(a0[4], a0[5], a0[6], a0[7]);
        *(float4*)&G[(gr + 1) * 128 + c0]     = make_float4(a1[0], a1[1], a1[2], a1[3]);
        *(float4*)&G[(gr + 1) * 128 + c0 + 4] = make_float4(a1[4], a1[5], a1[6], a1[7]);
    }
}

// ---------------------------------------------------------------------------
// KLAB: blocks 0..1023: dense argmax -> labels[s] (u8, 255 = ungated).
//       16-lane group per sample (4 samples per wave instruction stream),
//       unconditional clamped-address 2-deep prefetch (counted vmcnt works).
//       block 1024: Gauss-Jordan inversion of G -> W (hidden under the sweep).
// ---------------------------------------------------------------------------
extern "C" __global__ __launch_bounds__(256)
void klab(const float* __restrict__ logits, const void* __restrict__ mask,
          char* __restrict__ ws)
{
    __shared__ float prA[128], prB[128], pcA[128], pcB[128];
    __shared__ int sIsBool;
    const int tid = threadIdx.x;

    if (blockIdx.x == 1024) {
        // ---- Gauss-Jordan inversion, 256 threads, gg fully register-resident ----
        const float* G = (const float*)(ws + OFF_G);
        float* W = (float*)(ws + OFF_W);
        float gg[8][8];
        const int r0 = 8 * (tid >> 4), c0 = 8 * (tid & 15);
        #pragma unroll
        for (int ii = 0; ii < 8; ++ii) {
            *(float4*)&gg[ii][0] = *(const float4*)&G[(r0 + ii) * 128 + c0];
            *(float4*)&gg[ii][4] = *(const float4*)&G[(r0 + ii) * 128 + c0 + 4];
        }
        if (r0 == 0) {
            #pragma unroll
            for (int j = 0; j < 8; ++j) prA[c0 + j] = gg[0][j];
        }
        if (c0 == 0) {
            #pragma unroll
            for (int i = 0; i < 8; ++i) pcA[r0 + i] = gg[i][0];
        }
        __syncthreads();
        for (int k = 0; k < 128; ++k) {
            const float* pr = (k & 1) ? prB : prA;
            const float* pc = (k & 1) ? pcB : pcA;
            float rinv = 1.0f / pr[k];
            float rf[8], fc[8];
            #pragma unroll
            for (int j = 0; j < 8; ++j) { rf[j] = pr[c0 + j] * rinv; if (c0 + j == k) rf[j] = rinv; }
            #pragma unroll
            for (int i = 0; i < 8; ++i) fc[i] = pc[r0 + i];
            #pragma unroll
            for (int i = 0; i < 8; ++i) {
                if (r0 + i == k) {
                    #pragma unroll
                    for (int j = 0; j < 8; ++j) gg[i][j] = rf[j];
                } else {
                    float f = fc[i];
                    #pragma unroll
                    for (int j = 0; j < 8; ++j) {
                        float base = (c0 + j == k) ? 0.0f : gg[i][j];
                        gg[i][j] = base - f * rf[j];
                    }
                }
            }
            const int kn = k + 1;
            if (kn < 128) {
                float* prn = (kn & 1) ? prB : prA;
                float* pcn = (kn & 1) ? pcB : pcA;
                #pragma unroll
                for (int ii = 0; ii < 8; ++ii) {
                    if (r0 + ii == kn) {
                        #pragma unroll
                        for (int j = 0; j < 8; ++j) prn[c0 + j] = gg[ii][j];
                    }
                }
                #pragma unroll
                for (int jj = 0; jj < 8; ++jj) {
                    if (c0 + jj == kn) {
                        #pragma unroll
                        for (int i = 0; i < 8; ++i) pcn[r0 + i] = gg[i][jj];
                    }
                }
            }
            __syncthreads();
        }
        #pragma unroll
        for (int ii = 0; ii < 8; ++ii) {
            *(float4*)&W[(r0 + ii) * 128 + c0]     = *(float4*)&gg[ii][0];
            *(float4*)&W[(r0 + ii) * 128 + c0 + 4] = *(float4*)&gg[ii][4];
        }
        return;
    }

    // ---- label blocks ----
    unsigned char* labels = (unsigned char*)(ws + OFF_LAB);
    { // mask dtype sniff
        int v = 0;
        if (tid < 64) v = ((const int*)mask)[tid];
        unsigned long long bal = __ballot((unsigned)v > 1u);
        if (tid == 0) sIsBool = (bal != 0ull);
    }
    __syncthreads();
    const bool isBool = (sIsBool != 0);

    const int wave = tid >> 6, lane = tid & 63;
    const int base = blockIdx.x * 256 + wave * 64;   // 64 samples per wave

    int gv = isBool ? (int)((const unsigned char*)mask)[base + lane]
                    : ((const int*)mask)[base + lane];
    unsigned long long gmask = __ballot(gv != 0);

    const int smp = lane >> 4;          // which of 4 samples in the group
    const int c4  = 4 * (lane & 15);    // column base within row
    const float4* lp4 = (const float4*)logits;   // 32 float4 per row

    // prefetch groups 0 and 1 (row = base + 4*g + smp, cols [c4,c4+4) and [64+c4,..))
    size_t r0i = (size_t)(base + smp) * 32 + (c4 >> 2);
    size_t r1i = (size_t)(base + 4 + smp) * 32 + (c4 >> 2);
    float4 a0 = lp4[r0i], b0 = lp4[r0i + 16];
    float4 a1 = lp4[r1i], b1 = lp4[r1i + 16];

    #pragma unroll
    for (int g = 0; g < 16; ++g) {
        float4 ca = a0, cb = b0;
        a0 = a1; b0 = b1;
        int pg = (g + 2 < 16) ? g + 2 : 15;          // clamped -> loads unconditional
        size_t rpi = (size_t)(base + 4 * pg + smp) * 32 + (c4 >> 2);
        a1 = lp4[rpi]; b1 = lp4[rpi + 16];

        // within-lane argmax of 8 values (dims ascending -> strict > keeps first)
        float m = ca.x; int id = c4;
        if (ca.y > m) { m = ca.y; id = c4 + 1; }
        if (ca.z > m) { m = ca.z; id = c4 + 2; }
        if (ca.w > m) { m = ca.w; id = c4 + 3; }
        if (cb.x > m) { m = cb.x; id = 64 + c4; }
        if (cb.y > m) { m = cb.y; id = 64 + c4 + 1; }
        if (cb.z > m) { m = cb.z; id = 64 + c4 + 2; }
        if (cb.w > m) { m = cb.w; id = 64 + c4 + 3; }
        // 16-lane butterfly (xor<16 stays in group), smaller dim wins ties
        #pragma unroll
        for (int off = 1; off < 16; off <<= 1) {
            float om = __shfl_xor(m, off);
            int   oi = __shfl_xor(id, off);
            if (om > m || (om == m && oi < id)) { m = om; id = oi; }
        }
        if ((lane & 15) == 0) {
            int s = base + 4 * g + smp;
            bool gt = (gmask >> (4 * g + smp)) & 1ull;
            labels[s] = gt ? (unsigned char)id : (unsigned char)255;
        }
    }
}

// ---------------------------------------------------------------------------
// KSEG: dense img stream + gated LDS segment-sum. 256 blocks x 1024 threads.
//       Wave owns 64 samples; 4 rows per group, 2-deep unconditional prefetch
//       (8KB in flight per wave). Labels broadcast via one __shfl per sample.
//       Permuted acc layout (dim 4L+j -> slot j*64+L) = conflict-free ds_add.
// ---------------------------------------------------------------------------
extern "C" __global__ __launch_bounds__(1024)
void kseg(const float* __restrict__ img, char* __restrict__ ws, int nSlab)
{
    __shared__ float acc[CCLS][DDIM];   // 128 KB
    __shared__ int cnts[CCLS];
    const int b = blockIdx.x, tid = threadIdx.x;
    const unsigned char* labels = (const unsigned char*)(ws + OFF_LAB);

    {
        float4 z = make_float4(0.f, 0.f, 0.f, 0.f);
        for (int i = tid; i < 8192; i += 1024) ((float4*)acc)[i] = z;
        if (tid < CCLS) cnts[tid] = 0;
    }
    __syncthreads();

    const int wave = tid >> 6, lane = tid & 63;
    const int base = b * 1024 + wave * 64;
    const float4* im4 = (const float4*)img;      // 64 float4 per row

    int labByte = labels[base + lane];           // own sample's label

    size_t rb0 = (size_t)base * 64 + lane;
    float4 c0 = im4[rb0], c1 = im4[rb0 + 64], c2 = im4[rb0 + 128], c3 = im4[rb0 + 192];
    size_t rb1 = rb0 + 256;
    float4 n0 = im4[rb1], n1 = im4[rb1 + 64], n2 = im4[rb1 + 128], n3 = im4[rb1 + 192];

    #pragma unroll
    for (int g = 0; g < 16; ++g) {
        float4 u0 = c0, u1 = c1, u2 = c2, u3 = c3;
        c0 = n0; c1 = n1; c2 = n2; c3 = n3;
        int pg = (g + 2 < 16) ? g + 2 : 15;      // clamped -> unconditional loads
        size_t rp = (size_t)(base + 4 * pg) * 64 + lane;
        n0 = im4[rp]; n1 = im4[rp + 64]; n2 = im4[rp + 128]; n3 = im4[rp + 192];

        #pragma unroll
        for (int u = 0; u < 4; ++u) {
            int lb = __shfl(labByte, 4 * g + u);
            float4 v = (u == 0) ? u0 : (u == 1) ? u1 : (u == 2) ? u2 : u3;
            if (lb != 255) {                      // wave-uniform branch
                atomicAdd(&acc[lb][lane],        v.x);
                atomicAdd(&acc[lb][64 + lane],   v.y);
                atomicAdd(&acc[lb][128 + lane],  v.z);
                atomicAdd(&acc[lb][192 + lane],  v.w);
                if (lane == 0) atomicAdd(&cnts[lb], 1);
            }
        }
    }
    __syncthreads();

    const float* accF = &acc[0][0];
    if (nSlab == 256) {
        float4* pp = (float4*)((float*)(ws + OFF_BIG) + (size_t)b * SLAB_FLOATS);
        for (int i = tid; i < 8192; i += 1024) pp[i] = ((const float4*)accF)[i];
    } else {
        float* slab = (float*)(ws + OFF_BIG) + (size_t)(b % nSlab) * SLAB_FLOATS;
        for (int i = tid; i < SLAB_FLOATS; i += 1024)
            if (accF[i] != 0.f) unsafeAtomicAdd(&slab[i], accF[i]);
    }
    if (tid < CCLS && cnts[tid]) atomicAdd(&((int*)(ws + OFF_COUNTS))[tid], cnts[tid]);
}

// ---------------------------------------------------------------------------
// KB: reduce slabs -> class means Mraw (un-permuting dim layout)
// ---------------------------------------------------------------------------
extern "C" __global__ __launch_bounds__(128)
void kb_means(char* __restrict__ ws, int nSlab)
{
    const int idx = blockIdx.x * 128 + threadIdx.x;   // [0, 32768)
    const float* p = (const float*)(ws + OFF_BIG) + idx;
    float a = 0.f;
    for (int pb = 0; pb < nSlab; ++pb) a += p[(size_t)pb * SLAB_FLOATS];
    const int c = idx >> 8, slot = idx & 255;
    const int* counts = (const int*)(ws + OFF_COUNTS);
    const int d = 4 * (slot & 63) + (slot >> 6);      // unpermute
    float cf = fmaxf((float)counts[c], 1.0f);
    ((float*)(ws + OFF_MRAW))[c * 256 + d] = a / cf;
}

// K4: B = Mraw @ T^T  (128x128)
extern "C" __global__ __launch_bounds__(128)
void k4_B(char* __restrict__ ws)
{
    __shared__ float mr[256];
    const int c = blockIdx.x, j = threadIdx.x;
    const float* Mraw = (const float*)(ws + OFF_MRAW);
    const float* Tt = (const float*)(ws + OFF_TT);
    mr[j] = Mraw[c * 256 + j]; mr[j + 128] = Mraw[c * 256 + 128 + j];
    __syncthreads();
    float a = 0.f;
    #pragma unroll 8
    for (int d = 0; d < 256; ++d) a += mr[d] * Tt[d * 128 + j];
    ((float*)(ws + OFF_B))[c * 128 + j] = a;
}

// K5: Zt = (B @ W)^T = W @ B^T   (W symmetric)
extern "C" __global__ __launch_bounds__(128)
void k5_Z(char* __restrict__ ws)
{
    __shared__ float bc[128];
    const int c = blockIdx.x, j = threadIdx.x;
    const float* B = (const float*)(ws + OFF_B);
    const float* W = (const float*)(ws + OFF_W);
    bc[j] = B[c * 128 + j];
    __syncthreads();
    float a = 0.f;
    #pragma unroll 8
    for (int k = 0; k < 128; ++k) a += bc[k] * W[k * 128 + j];
    ((float*)(ws + OFF_ZT))[j * 128 + c] = a;
}

// K6: M = B @ Zt = B W B^T
extern "C" __global__ __launch_bounds__(128)
void k6_M(char* __restrict__ ws)
{
    __shared__ float bc[128];
    const int c = blockIdx.x, j = threadIdx.x;
    const float* B = (const float*)(ws + OFF_B);
    const float* Zt = (const float*)(ws + OFF_ZT);
    bc[j] = B[c * 128 + j];
    __syncthreads();
    float a = 0.f;
    #pragma unroll 8
    for (int k = 0; k < 128; ++k) a += bc[k] * Zt[k * 128 + j];
    ((float*)(ws + OFF_M))[c * 128 + j] = a;
}

// K7: loss
extern "C" __global__ __launch_bounds__(256)
void k7_loss(char* __restrict__ ws, float* __restrict__ out)
{
    __shared__ float norms[128];
    __shared__ int pres[128];
    __shared__ float wsum[4];
    const int tid = threadIdx.x;
    const float* M = (const float*)(ws + OFF_M);
    const int* counts = (const int*)(ws + OFF_COUNTS);
    if (tid < 128) {
        int p = counts[tid] > 0;
        pres[tid] = p;
        norms[tid] = sqrtf(p ? M[tid * 129] : 1.0f);
    }
    __syncthreads();
    float ls = 0.f;
    for (int idx = tid; idx < 16384; idx += 256) {
        int c = idx >> 7, j = idx & 127;
        if (c != j && pres[c] && pres[j])
            ls += 1.0f - M[idx] / ((norms[c] + EPSF) * (norms[j] + EPSF));
    }
    #pragma unroll
    for (int off = 32; off > 0; off >>= 1) ls += __shfl_down(ls, off);
    if ((tid & 63) == 0) wsum[tid >> 6] = ls;
    __syncthreads();
    if (tid == 0) {
        int np = 0;
        for (int c = 0; c < 128; ++c) np += pres[c];
        float tot = wsum[0] + wsum[1] + wsum[2] + wsum[3];
        out[0] = (np >= 2) ? tot : 0.0f;
    }
}

// ---------------------------------------------------------------------------
extern "C" void kernel_launch(void* const* d_in, const int* in_sizes, int n_in,
                              void* d_out, int out_size, void* d_ws, size_t ws_size,
                              hipStream_t stream)
{
    const float* logits = (const float*)d_in[0];
    const float* img    = (const float*)d_in[1];
    const float* T      = (const float*)d_in[2];
    const void*  mask   = d_in[3];
    char* ws = (char*)d_ws;

    size_t avail = (ws_size > (size_t)OFF_BIG) ? ws_size - OFF_BIG : 0;
    int nSlab = (int)(avail / (SLAB_FLOATS * 4));
    if (nSlab > 256) nSlab = 256;
    if (nSlab < 1) nSlab = 1;

    hipMemsetAsync(ws + OFF_COUNTS, 0, 512, stream);
    if (nSlab < 256)
        hipMemsetAsync(ws + OFF_BIG, 0, (size_t)nSlab * SLAB_FLOATS * 4, stream);

    kg_gram<<<4, 1024, 0, stream>>>(T, ws);
    klab<<<1025, 256, 0, stream>>>(logits, mask, ws);      // labels + hidden GJ inversion
    kseg<<<256, 1024, 0, stream>>>(img, ws, nSlab);
    kb_means<<<256, 128, 0, stream>>>(ws, nSlab);
    k4_B<<<128, 128, 0, stream>>>(ws);
    k5_Z<<<128, 128, 0, stream>>>(ws);
    k6_M<<<128, 128, 0, stream>>>(ws);
    k7_loss<<<1, 256, 0, stream>>>(ws, (float*)d_out);
}

// Round 6
// 372.996 us; speedup vs baseline: 1.3361x; 1.3361x over previous
//
#include <hip/hip_runtime.h>

// Problem constants
#define NSAMP 262144
#define CCLS 128
#define DDIM 256
#define EPSF 1e-8f

// ws byte offsets
#define OFF_COUNTS 0u         // 128 * u32
#define OFF_SUMS   2048u      // 128x256 f32 sums -> ends 133120 (memset covers [0,133120))
#define OFF_G      133120u    // 128x128 f32
#define OFF_W      198656u    // 128x128 f32 (G^-1)
#define OFF_TT     264192u    // 256x128 f32 (T transposed)
#define OFF_B      395264u    // 128x128 f32 (Mraw @ T^T)
#define OFF_ZT     460800u    // 128x128 f32 (W @ B^T)
#define OFF_M      526336u    // 128x128 f32 (B W B^T)
#define OFF_LAB    1048576u   // 262144 u8 labels (255 = ungated)

// ---------------------------------------------------------------------------
// KLAB: blocks 0..1023 (256 thr): dense argmax -> labels[s] (u8, 255=ungated).
//       blocks 1024..1027: G = T*T^T rows [32g,32g+32) + T^T chunk g.
// ---------------------------------------------------------------------------
extern "C" __global__ __launch_bounds__(256)
void klab(const float* __restrict__ logits, const float* __restrict__ T,
          const void* __restrict__ mask, char* __restrict__ ws)
{
    const int tid = threadIdx.x;

    if (blockIdx.x >= 1024) {
        // ---- Gram block (256 threads) ----
        __shared__ float Tl[64][132];
        const int g = blockIdx.x - 1024;
        float* Tt = (float*)(ws + OFF_TT);
        float* G  = (float*)(ws + OFF_G);
        float a0[8], a1[8];
        #pragma unroll
        for (int j = 0; j < 8; ++j) { a0[j] = 0.f; a1[j] = 0.f; }
        const int Lr = 2 * (tid >> 4);
        const int c0 = 8 * (tid & 15);
        for (int ch = 0; ch < 4; ++ch) {
            for (int i = tid; i < 8192; i += 256) {
                int cc = i >> 6, dd = i & 63;
                Tl[dd][cc] = T[cc * 256 + ch * 64 + dd];
            }
            __syncthreads();
            if (g == ch) {
                for (int i = tid; i < 8192; i += 256) {
                    int c2 = i & 127, d2 = i >> 7;
                    Tt[(ch * 64 + d2) * 128 + c2] = Tl[d2][c2];
                }
            }
            for (int dd = 0; dd < 64; ++dd) {
                float r0 = Tl[dd][32 * g + Lr];
                float r1 = Tl[dd][32 * g + Lr + 1];
                float cv[8];
                *(float4*)&cv[0] = *(const float4*)&Tl[dd][c0];
                *(float4*)&cv[4] = *(const float4*)&Tl[dd][c0 + 4];
                #pragma unroll
                for (int j = 0; j < 8; ++j) { a0[j] += r0 * cv[j]; a1[j] += r1 * cv[j]; }
            }
            __syncthreads();
        }
        int gr = 32 * g + Lr;
        *(float4*)&G[gr * 128 + c0]           = make_float4(a0[0], a0[1], a0[2], a0[3]);
        *(float4*)&G[gr * 128 + c0 + 4]       = make_float4(a0[4], a0[5], a0[6], a0[7]);
        *(float4*)&G[(gr + 1) * 128 + c0]     = make_float4(a1[0], a1[1], a1[2], a1[3]);
        *(float4*)&G[(gr + 1) * 128 + c0 + 4] = make_float4(a1[4], a1[5], a1[6], a1[7]);
        return;
    }

    // ---- label blocks ----
    __shared__ int sIsBool;
    unsigned char* labels = (unsigned char*)(ws + OFF_LAB);
    { // mask dtype sniff
        int v = 0;
        if (tid < 64) v = ((const int*)mask)[tid];
        unsigned long long bal = __ballot((unsigned)v > 1u);
        if (tid == 0) sIsBool = (bal != 0ull);
    }
    __syncthreads();
    const bool isBool = (sIsBool != 0);

    const int wave = tid >> 6, lane = tid & 63;
    const int base = blockIdx.x * 256 + wave * 64;   // 64 samples per wave

    int gv = isBool ? (int)((const unsigned char*)mask)[base + lane]
                    : ((const int*)mask)[base + lane];
    unsigned long long gmask = __ballot(gv != 0);

    const int smp = lane >> 4;          // which of 4 samples in the group
    const int c4  = 4 * (lane & 15);    // column base within row
    const float4* lp4 = (const float4*)logits;   // 32 float4 per row

    size_t r0i = (size_t)(base + smp) * 32 + (c4 >> 2);
    size_t r1i = (size_t)(base + 4 + smp) * 32 + (c4 >> 2);
    float4 a0 = lp4[r0i], b0 = lp4[r0i + 16];
    float4 a1 = lp4[r1i], b1 = lp4[r1i + 16];

    #pragma unroll
    for (int g = 0; g < 16; ++g) {
        float4 ca = a0, cb = b0;
        a0 = a1; b0 = b1;
        int pg = (g + 2 < 16) ? g + 2 : 15;          // clamped -> loads unconditional
        size_t rpi = (size_t)(base + 4 * pg + smp) * 32 + (c4 >> 2);
        a1 = lp4[rpi]; b1 = lp4[rpi + 16];

        float m = ca.x; int id = c4;
        if (ca.y > m) { m = ca.y; id = c4 + 1; }
        if (ca.z > m) { m = ca.z; id = c4 + 2; }
        if (ca.w > m) { m = ca.w; id = c4 + 3; }
        if (cb.x > m) { m = cb.x; id = 64 + c4; }
        if (cb.y > m) { m = cb.y; id = 64 + c4 + 1; }
        if (cb.z > m) { m = cb.z; id = 64 + c4 + 2; }
        if (cb.w > m) { m = cb.w; id = 64 + c4 + 3; }
        #pragma unroll
        for (int off = 1; off < 16; off <<= 1) {
            float om = __shfl_xor(m, off);
            int   oi = __shfl_xor(id, off);
            if (om > m || (om == m && oi < id)) { m = om; id = oi; }
        }
        if ((lane & 15) == 0) {
            int s = base + 4 * g + smp;
            bool gt = (gmask >> (4 * g + smp)) & 1ull;
            labels[s] = gt ? (unsigned char)id : (unsigned char)255;
        }
    }
}

// ---------------------------------------------------------------------------
// KSEG: blocks 0..511 = (256 sample-ranges x 2 D-halves). Each wave owns an
//       8-class octet; accumulators live in 16 statically-indexed VGPRs.
//       Hot loop: label byte load + ballot + bit-scan gather of accepted rows
//       (float2/lane), branchless cndmask accumulate. ZERO LDS/shfl/ds-atomic
//       in the loop. Flush: 16 global f32 atomics per wave into sums.
//       Block 512: Gauss-Jordan inversion of G -> W (register-resident).
// ---------------------------------------------------------------------------
extern "C" __global__ __launch_bounds__(1024)
void kseg(const float* __restrict__ img, char* __restrict__ ws)
{
    const int tid = threadIdx.x;

    if (blockIdx.x == 512) {
        // ---- Gauss-Jordan inversion (compute in tid<256, barriers all) ----
        __shared__ float prA[128], prB[128], pcA[128], pcB[128];
        const float* G = (const float*)(ws + OFF_G);
        float* W = (float*)(ws + OFF_W);
        float gg[8][8];
        const int r0 = 8 * (tid >> 4), c0 = 8 * (tid & 15);
        if (tid < 256) {
            #pragma unroll
            for (int ii = 0; ii < 8; ++ii) {
                *(float4*)&gg[ii][0] = *(const float4*)&G[(r0 + ii) * 128 + c0];
                *(float4*)&gg[ii][4] = *(const float4*)&G[(r0 + ii) * 128 + c0 + 4];
            }
            if (r0 == 0) {
                #pragma unroll
                for (int j = 0; j < 8; ++j) prA[c0 + j] = gg[0][j];
            }
            if (c0 == 0) {
                #pragma unroll
                for (int i = 0; i < 8; ++i) pcA[r0 + i] = gg[i][0];
            }
        }
        __syncthreads();
        for (int k = 0; k < 128; ++k) {
            if (tid < 256) {
                const float* pr = (k & 1) ? prB : prA;
                const float* pc = (k & 1) ? pcB : pcA;
                float rinv = 1.0f / pr[k];
                float rf[8], fc[8];
                #pragma unroll
                for (int j = 0; j < 8; ++j) { rf[j] = pr[c0 + j] * rinv; if (c0 + j == k) rf[j] = rinv; }
                #pragma unroll
                for (int i = 0; i < 8; ++i) fc[i] = pc[r0 + i];
                #pragma unroll
                for (int i = 0; i < 8; ++i) {
                    if (r0 + i == k) {
                        #pragma unroll
                        for (int j = 0; j < 8; ++j) gg[i][j] = rf[j];
                    } else {
                        float f = fc[i];
                        #pragma unroll
                        for (int j = 0; j < 8; ++j) {
                            float base = (c0 + j == k) ? 0.0f : gg[i][j];
                            gg[i][j] = base - f * rf[j];
                        }
                    }
                }
                const int kn = k + 1;
                if (kn < 128) {
                    float* prn = (kn & 1) ? prB : prA;
                    float* pcn = (kn & 1) ? pcB : pcA;
                    #pragma unroll
                    for (int ii = 0; ii < 8; ++ii) {
                        if (r0 + ii == kn) {
                            #pragma unroll
                            for (int j = 0; j < 8; ++j) prn[c0 + j] = gg[ii][j];
                        }
                    }
                    #pragma unroll
                    for (int jj = 0; jj < 8; ++jj) {
                        if (c0 + jj == kn) {
                            #pragma unroll
                            for (int i = 0; i < 8; ++i) pcn[r0 + i] = gg[i][jj];
                        }
                    }
                }
            }
            __syncthreads();
        }
        if (tid < 256) {
            #pragma unroll
            for (int ii = 0; ii < 8; ++ii) {
                *(float4*)&W[(r0 + ii) * 128 + c0]     = *(float4*)&gg[ii][0];
                *(float4*)&W[(r0 + ii) * 128 + c0 + 4] = *(float4*)&gg[ii][4];
            }
        }
        return;
    }

    // ---- segment-sum blocks ----
    const int b = blockIdx.x;
    const int range = b >> 1, h = b & 1;        // sample range x D-half
    const int wave = tid >> 6, lane = tid & 63;
    const unsigned char* labels = (const unsigned char*)(ws + OFF_LAB);
    const float2* im2 = (const float2*)img;     // 128 float2 per row
    const int sbase = range * 1024;

    float accx[8], accy[8]; int cnt[8];
    #pragma unroll
    for (int c = 0; c < 8; ++c) { accx[c] = 0.f; accy[c] = 0.f; cnt[c] = 0; }

    for (int ch = 0; ch < 16; ++ch) {
        const int s64 = sbase + ch * 64;
        int lab = labels[s64 + lane];
        unsigned long long mb = __ballot((lab >> 3) == wave);   // my octet (255>>3=31 excluded)
        while (mb) {
            int bit = (int)(__ffsll((long long)mb) - 1); mb &= mb - 1;
            int s = s64 + bit;
            int lc = labels[s] & 7;                             // uniform broadcast load
            float2 v = im2[(size_t)s * 128 + h * 64 + lane];
            #pragma unroll
            for (int c = 0; c < 8; ++c) {
                bool p = (lc == c);
                accx[c] += p ? v.x : 0.f;
                accy[c] += p ? v.y : 0.f;
                cnt[c]  += p ? 1 : 0;
            }
        }
    }

    float* sums = (float*)(ws + OFF_SUMS);
    #pragma unroll
    for (int c = 0; c < 8; ++c) {
        const int cls = wave * 8 + c;
        unsafeAtomicAdd(&sums[cls * 256 + h * 128 + 2 * lane],     accx[c]);
        unsafeAtomicAdd(&sums[cls * 256 + h * 128 + 2 * lane + 1], accy[c]);
    }
    if (h == 0 && lane == 0) {
        int* counts = (int*)(ws + OFF_COUNTS);
        #pragma unroll
        for (int c = 0; c < 8; ++c)
            if (cnt[c]) atomicAdd(&counts[wave * 8 + c], cnt[c]);
    }
}

// K4: B = (sums/counts) @ T^T  (mean-divide fused; Mraw never materialized)
extern "C" __global__ __launch_bounds__(128)
void k4_B(char* __restrict__ ws)
{
    __shared__ float mr[256];
    const int c = blockIdx.x, j = threadIdx.x;
    const float* sums = (const float*)(ws + OFF_SUMS);
    const int* counts = (const int*)(ws + OFF_COUNTS);
    const float* Tt = (const float*)(ws + OFF_TT);
    float rcp = 1.0f / fmaxf((float)counts[c], 1.0f);
    mr[j] = sums[c * 256 + j] * rcp;
    mr[j + 128] = sums[c * 256 + 128 + j] * rcp;
    __syncthreads();
    float a = 0.f;
    #pragma unroll 8
    for (int d = 0; d < 256; ++d) a += mr[d] * Tt[d * 128 + j];
    ((float*)(ws + OFF_B))[c * 128 + j] = a;
}

// K5: Zt = (B @ W)^T = W @ B^T   (W symmetric)
extern "C" __global__ __launch_bounds__(128)
void k5_Z(char* __restrict__ ws)
{
    __shared__ float bc[128];
    const int c = blockIdx.x, j = threadIdx.x;
    const float* B = (const float*)(ws + OFF_B);
    const float* W = (const float*)(ws + OFF_W);
    bc[j] = B[c * 128 + j];
    __syncthreads();
    float a = 0.f;
    #pragma unroll 8
    for (int k = 0; k < 128; ++k) a += bc[k] * W[k * 128 + j];
    ((float*)(ws + OFF_ZT))[j * 128 + c] = a;
}

// K6: M = B @ Zt = B W B^T
extern "C" __global__ __launch_bounds__(128)
void k6_M(char* __restrict__ ws)
{
    __shared__ float bc[128];
    const int c = blockIdx.x, j = threadIdx.x;
    const float* B = (const float*)(ws + OFF_B);
    const float* Zt = (const float*)(ws + OFF_ZT);
    bc[j] = B[c * 128 + j];
    __syncthreads();
    float a = 0.f;
    #pragma unroll 8
    for (int k = 0; k < 128; ++k) a += bc[k] * Zt[k * 128 + j];
    ((float*)(ws + OFF_M))[c * 128 + j] = a;
}

// K7: loss
extern "C" __global__ __launch_bounds__(256)
void k7_loss(char* __restrict__ ws, float* __restrict__ out)
{
    __shared__ float norms[128];
    __shared__ int pres[128];
    __shared__ float wsum[4];
    const int tid = threadIdx.x;
    const float* M = (const float*)(ws + OFF_M);
    const int* counts = (const int*)(ws + OFF_COUNTS);
    if (tid < 128) {
        int p = counts[tid] > 0;
        pres[tid] = p;
        norms[tid] = sqrtf(p ? M[tid * 129] : 1.0f);
    }
    __syncthreads();
    float ls = 0.f;
    for (int idx = tid; idx < 16384; idx += 256) {
        int c = idx >> 7, j = idx & 127;
        if (c != j && pres[c] && pres[j])
            ls += 1.0f - M[idx] / ((norms[c] + EPSF) * (norms[j] + EPSF));
    }
    #pragma unroll
    for (int off = 32; off > 0; off >>= 1) ls += __shfl_down(ls, off);
    if ((tid & 63) == 0) wsum[tid >> 6] = ls;
    __syncthreads();
    if (tid == 0) {
        int np = 0;
        for (int c = 0; c < 128; ++c) np += pres[c];
        float tot = wsum[0] + wsum[1] + wsum[2] + wsum[3];
        out[0] = (np >= 2) ? tot : 0.0f;
    }
}

// ---------------------------------------------------------------------------
extern "C" void kernel_launch(void* const* d_in, const int* in_sizes, int n_in,
                              void* d_out, int out_size, void* d_ws, size_t ws_size,
                              hipStream_t stream)
{
    const float* logits = (const float*)d_in[0];
    const float* img    = (const float*)d_in[1];
    const float* T      = (const float*)d_in[2];
    const void*  mask   = d_in[3];
    char* ws = (char*)d_ws;

    hipMemsetAsync(ws, 0, 133120, stream);                 // counts + sums

    klab<<<1028, 256, 0, stream>>>(logits, T, mask, ws);   // labels + G/T^T
    kseg<<<513, 1024, 0, stream>>>(img, ws);               // reg-acc segsum + GJ inv
    k4_B<<<128, 128, 0, stream>>>(ws);
    k5_Z<<<128, 128, 0, stream>>>(ws);
    k6_M<<<128, 128, 0, stream>>>(ws);
    k7_loss<<<1, 256, 0, stream>>>(ws, (float*)d_out);
}